// Round 20
// baseline (632.146 us; speedup 1.0000x reference)
//
#include <hip/hip_runtime.h>
#include <hip/hip_bf16.h>
#include <math.h>

typedef unsigned short u16;
typedef __attribute__((ext_vector_type(8))) short bf16x8;
typedef __attribute__((ext_vector_type(4))) float f32x4;

// ---------- helpers ----------
__device__ __forceinline__ u16 f2bf(float f) {
  union { float f; unsigned u; } x; x.f = f;
  unsigned r = x.u + 0x7fffu + ((x.u >> 16) & 1u);
  return (u16)(r >> 16);
}
__device__ __forceinline__ float bf2f(u16 h) {
  union { unsigned u; float f; } x; x.u = ((unsigned)h) << 16;
  return x.f;
}
__device__ __forceinline__ float sigmf(float x) {
  x = fminf(fmaxf(x, -30.f), 30.f);
  return 1.f / (1.f + __expf(-x));
}
__device__ __forceinline__ float tanh_fast(float x) {
  x = fminf(fmaxf(x, -15.f), 15.f);
  float t = __expf(2.f * x);
  return (t - 1.f) / (t + 1.f);
}

// counted vmcnt wait (T4)
template<int N> __device__ __forceinline__ void wait_vmcnt() {
  if constexpr (N == 0)       asm volatile("s_waitcnt vmcnt(0)" ::: "memory");
  else if constexpr (N == 4)  asm volatile("s_waitcnt vmcnt(4)" ::: "memory");
  else if constexpr (N == 6)  asm volatile("s_waitcnt vmcnt(6)" ::: "memory");
  else if constexpr (N == 8)  asm volatile("s_waitcnt vmcnt(8)" ::: "memory");
  else static_assert(N == 0, "add vmcnt case");
}

// ---------- problem constants ----------
#define NB 4
#define DE 128
#define DO_ 512
#define HW 1560
#define THW 6240
#define NP 1664   // HW padded to 13*128
#define KP 6272   // THW padded to 49*128
#define PROP 5
#define PVSPLIT 7
#define PVKC 896  // 6272/7 = 28*32
#define SCALE 0.08838834764831845f

// ---------- generic bf16 GEMM core: C[M,N] = A[M,K] * Bt[N,K]^T ----------
// Tile BMT x 128, K-step BKT, 4 waves, 16x16x32 MFMA, global_load_lds
// double-buffer, counted vmcnt + raw barriers (chain kernels, 3D grid).
template<int MODE, int BMT, int BKT>
__device__ __forceinline__
void gemm_core(const u16* __restrict__ A, const u16* __restrict__ Bt,
               int K, int lda, int ldb, long a_bs, long b_bs,
               void* __restrict__ out0v, long o0_bs, int ld0,
               u16* __restrict__ out1, long o1_bs, int ld1,
               u16* __restrict__ out2, long o2_bs,
               const void* __restrict__ e0v, long e0_bs,
               const void* __restrict__ e1v, long e1_bs,
               const void* __restrict__ e2v, long e2_bs,
               const void* __restrict__ e3v, long e3_bs,
               int nvalid, float scale)
{
  constexpr int WR = BMT / 64;        // wave rows (2 or 1)
  constexpr int WC = 4 / WR;          // wave cols (2 or 4)
  constexpr int NF = 8 / WC;          // 16-wide n-frags per wave
  constexpr int KK = BKT / 32;        // k-subtiles per step
  constexpr int ASLOT = BMT * BKT / 8;
  constexpr int BSLOT = 128 * BKT / 8;
  constexpr int NISS = (ASLOT + BSLOT) / 256;
  constexpr int RSH = (BMT == 128) ? 7 : 6;
  __shared__ u16 lds[2][ASLOT + BSLOT][8];

  const int tid = threadIdx.x;
  const int wave = tid >> 6, lane = tid & 63;
  const int kg = lane >> 4, lr = lane & 15;
  const int wrw = wave / WC, wcw = wave % WC;
  const long b = blockIdx.z;
  const int m0 = blockIdx.x * BMT, n0 = blockIdx.y * 128;
  A += b * a_bs; Bt += b * b_bs;

  float* out0f = (float*)out0v;
  u16* out0h = (u16*)out0v;
  const float* e0f = (const float*)e0v;
  const u16* e0h = (const u16*)e0v;
  const u16* e1h = (const u16*)e1v;
  const u16* e2h = (const u16*)e2v;
  const u16* e3h = (const u16*)e3v;

  auto stage = [&](int buf, int kt) {
#pragma unroll
    for (int i = 0; i < NISS; ++i) {
      int s = tid + 256 * i;
      const u16* src;
      if (s < ASLOT) {
        int row = s & (BMT - 1), g = s >> RSH;
        src = A + (long)(m0 + row) * lda + kt + g * 8;
      } else {
        int s2 = s - ASLOT;
        int row = s2 & 127, g = s2 >> 7;
        src = Bt + (long)(n0 + row) * ldb + kt + g * 8;
      }
      __builtin_amdgcn_global_load_lds(
          (const __attribute__((address_space(1))) void*)src,
          (__attribute__((address_space(3))) void*)&lds[buf][wave * 64 + 256 * i][0],
          16, 0, 0);
    }
  };

  f32x4 acc[4][NF];
#pragma unroll
  for (int m = 0; m < 4; ++m)
#pragma unroll
    for (int n = 0; n < NF; ++n) acc[m][n] = (f32x4){0.f, 0.f, 0.f, 0.f};

  const int nt = K / BKT;
  stage(0, 0);
  for (int t = 0; t < nt; ++t) {
    int cur = t & 1;
    if (t + 1 < nt) {
      stage(cur ^ 1, (t + 1) * BKT);   // next tile stays in flight across barrier
      wait_vmcnt<NISS>();
    } else {
      wait_vmcnt<0>();
    }
    __builtin_amdgcn_s_barrier();
    bf16x8 af[KK][4], bfr[KK][NF];
#pragma unroll
    for (int kk = 0; kk < KK; ++kk) {
#pragma unroll
      for (int m = 0; m < 4; ++m)
        af[kk][m] = *(const bf16x8*)&lds[cur][(kk * 4 + kg) * BMT + wrw * 64 + m * 16 + lr][0];
#pragma unroll
      for (int n = 0; n < NF; ++n)
        bfr[kk][n] = *(const bf16x8*)&lds[cur][ASLOT + (kk * 4 + kg) * 128 + (wcw * NF + n) * 16 + lr][0];
    }
#pragma unroll
    for (int kk = 0; kk < KK; ++kk)
#pragma unroll
      for (int m = 0; m < 4; ++m)
#pragma unroll
        for (int n = 0; n < NF; ++n)
          acc[m][n] = __builtin_amdgcn_mfma_f32_16x16x32_bf16(af[kk][m], bfr[kk][n], acc[m][n], 0, 0, 0);
    __builtin_amdgcn_s_barrier();
  }

  // frag elem j -> row = m0+wrw*64+m*16+kg*4+j, col = n0+(wcw*NF+n)*16+lr
#pragma unroll
  for (int m = 0; m < 4; ++m) {
    int rloc = wrw * 64 + m * 16 + kg * 4;
#pragma unroll
    for (int n = 0; n < NF; ++n) {
      int col = n0 + (wcw * NF + n) * 16 + lr;
#pragma unroll
      for (int j = 0; j < 4; ++j) {
        long row = m0 + rloc + j;
        float v = acc[m][n][j];
        if constexpr (MODE == 2) {        // Chru(bf16) = memT @ Wruh^T + bias_ru
          out1[b * o1_bs + row * ld1 + col] = f2bf(v + e0f[col]);
        } else if constexpr (MODE == 3) { // gates r,u + cand-X partial
          if (col < 1024) {
            float gt = sigmf(v + bf2f(e0h[b * e0_bs + row * 1024 + col]));
            if (col < 512)                // r -> RH = r*mem into XR cols 512..1023
              out1[b * o1_bs + row * ld1 + 512 + col] =
                  f2bf(gt * bf2f(e1h[b * e1_bs + row * 512 + col]));
            else                          // u -> U (bf16)
              out0h[b * o0_bs + row * ld0 + (col - 512)] = f2bf(gt);
          } else {                        // Cx = X @ Wc_x (raw logit partial)
            out2[b * o2_bs + row * 512 + (col - 1024)] = f2bf(v);
          }
        } else if constexpr (MODE == 4) { // candidate (RH half) + GRU update
          float cg = tanh_fast(v + bf2f(e3h[b * e3_bs + row * 512 + col]) + e0f[col]);
          float u = bf2f(e1h[b * e1_bs + row * 512 + col]);
          float mm = bf2f(e2h[b * e2_bs + row * 512 + col]);
          float x = mm * (1.f - u) + u * cg;
          out1[b * o1_bs + row * ld1 + col] = f2bf(x);
          // last layer: write d_out directly, transposed [b][col][row], row<HW
          if (out0f && row < nvalid)
            out0f[b * o0_bs + (long)col * ld0 + row] = x;
        }
      }
    }
  }
}

#define GEMM_ARGS                                                              \
  const u16* __restrict__ A, const u16* __restrict__ Bt, int K, int lda,       \
  int ldb, long a_bs, long b_bs, void* __restrict__ out0v, long o0_bs,         \
  int ld0, u16* __restrict__ out1, long o1_bs, int ld1,                        \
  u16* __restrict__ out2, long o2_bs,                                          \
  const void* __restrict__ e0v, long e0_bs, const void* __restrict__ e1v,      \
  long e1_bs, const void* __restrict__ e2v, long e2_bs,                        \
  const void* __restrict__ e3v, long e3_bs, int nvalid, float scale
#define GEMM_PASS A, Bt, K, lda, ldb, a_bs, b_bs, out0v, o0_bs, ld0, out1,     \
  o1_bs, ld1, out2, o2_bs, e0v, e0_bs, e1v, e1_bs, e2v, e2_bs, e3v, e3_bs,     \
  nvalid, scale

__global__ __launch_bounds__(256) void gk_chru(GEMM_ARGS)   { gemm_core<2, 64, 64>(GEMM_PASS); }
__global__ __launch_bounds__(256) void gk_gates(GEMM_ARGS)  { gemm_core<3, 128, 64>(GEMM_PASS); }
__global__ __launch_bounds__(256) void gk_cand(GEMM_ARGS)   { gemm_core<4, 64, 64>(GEMM_PASS); }

// ========== fused attention: Ppart[b,z] = exp(Q@K^T*s) @ moutb^T ==========
// Flash-style, COLUMN-SPLIT x2 for occupancy: each block does 64 q-rows x
// 256 o-cols (ch = col half) -> acc 64 AGPR + b_ 4 (was 128+8), ~160 regs
// -> 3 blocks/CU (launch_bounds(256,3)). S-phase duplicated across the two
// col-halves (+20% MFMA) -- cheap vs 1.5x TLP in a latency-bound kernel.
// Only ch==0 writes Zp. XCD pin keeps both halves of a (pair,mb) adjacent.
__global__ __launch_bounds__(256, 3)
void gemm_fa(const u16* __restrict__ qiT, const u16* __restrict__ miT,
             const u16* __restrict__ moutb,
             u16* __restrict__ Ppart, float* __restrict__ Zp)
{
  const int bid = blockIdx.x;            // 0..1455
  const int xcd = bid & 7, i = bid >> 3; // i 0..181
  const int s = xcd * 182 + i;           // 0..1455
  const int pm = s >> 1, ch = s & 1;     // pm 0..727, ch = col half
  const int pair = pm / 26, mb = pm - pair * 26;
  const int b = pair / PVSPLIT, z = pair - b * PVSPLIT;
  const int m0 = mb * 64;
  const int k0 = z * PVKC;               // 28 steps of 32 kv

  const int tid = threadIdx.x;
  const int wave = tid >> 6, lane = tid & 63;
  const int kg = lane >> 4, lr = lane & 15;

  __shared__ u16 ldsQ[1024 * 8];         // 16 KB, persistent
  __shared__ u16 ldsK[2][512 * 8];       // 8 KB each
  __shared__ u16 ldsP[64 * 40];          // [q][kv] pad-40 : 5 KB

  const u16* Qb = qiT + (long)b * NP * DE;
  const u16* Mb = miT + (long)b * KP * DE;
  // wave owns cols [ch*256 + wave*64, +64)
  const u16* B0 = moutb + (long)b * DO_ * KP +
                  (long)(ch * 256 + wave * 64 + lr) * KP + kg * 8;

  auto stageK = [&](int buf, int ts) {
#pragma unroll
    for (int i2 = 0; i2 < 2; ++i2) {
      int s2 = tid + 256 * i2;             // 0..511
      int row = s2 & 31, g = s2 >> 5;
      const u16* src = Mb + (long)(k0 + ts * 32 + row) * DE + g * 8;
      __builtin_amdgcn_global_load_lds(
          (const __attribute__((address_space(1))) void*)src,
          (__attribute__((address_space(3))) void*)&ldsK[buf][(wave * 64 + 256 * i2) * 8],
          16, 0, 0);
    }
  };

  // prologue: stage Q (once) + Kc(0); full drain + barrier
#pragma unroll
  for (int i2 = 0; i2 < 4; ++i2) {
    int s2 = tid + 256 * i2;               // 0..1023
    int row = s2 & 63, g = s2 >> 6;
    const u16* src = Qb + (long)(m0 + row) * DE + g * 8;
    __builtin_amdgcn_global_load_lds(
        (const __attribute__((address_space(1))) void*)src,
        (__attribute__((address_space(3))) void*)&ldsQ[(wave * 64 + 256 * i2) * 8],
        16, 0, 0);
  }
  stageK(0, 0);
  __syncthreads();

  f32x4 acc[4][4];
#pragma unroll
  for (int m = 0; m < 4; ++m)
#pragma unroll
    for (int n = 0; n < 4; ++n) acc[m][n] = (f32x4){0.f, 0.f, 0.f, 0.f};
  float zacc[4] = {0.f, 0.f, 0.f, 0.f};
  bf16x8 b_[4];

#define FA_STEP(T, CUR, DOS)                                                     \
  {                                                                              \
    _Pragma("unroll") for (int n = 0; n < 4; ++n)                                \
        b_[n] = *(const bf16x8*)&B0[(long)n * 16 * KP + k0 + (T) * 32];          \
    if (DOS) stageK((CUR) ^ 1, (T) + 1);                                         \
    bf16x8 qf[4], kc[2][4];                                                      \
    _Pragma("unroll") for (int kk = 0; kk < 4; ++kk)                             \
        qf[kk] = *(const bf16x8*)&ldsQ[((kk * 4 + kg) * 64 + wave * 16 + lr) * 8]; \
    _Pragma("unroll") for (int n = 0; n < 2; ++n)                                \
        _Pragma("unroll") for (int kk = 0; kk < 4; ++kk)                         \
            kc[n][kk] = *(const bf16x8*)&ldsK[CUR][((kk * 4 + kg) * 32 + n * 16 + lr) * 8]; \
    f32x4 sacc[2];                                                               \
    sacc[0] = (f32x4){0.f, 0.f, 0.f, 0.f};                                       \
    sacc[1] = (f32x4){0.f, 0.f, 0.f, 0.f};                                       \
    _Pragma("unroll") for (int kk = 0; kk < 4; ++kk)                             \
        _Pragma("unroll") for (int n = 0; n < 2; ++n)                            \
            sacc[n] = __builtin_amdgcn_mfma_f32_16x16x32_bf16(qf[kk], kc[n][kk], \
                                                              sacc[n], 0, 0, 0); \
    _Pragma("unroll") for (int n = 0; n < 2; ++n) {                              \
      bool valid = (k0 + (T) * 32 + n * 16 + lr) < THW;                          \
      _Pragma("unroll") for (int j = 0; j < 4; ++j) {                            \
        float pf = valid ? __expf(sacc[n][j] * SCALE) : 0.f;                     \
        zacc[j] += pf;                                                           \
        ldsP[(wave * 16 + kg * 4 + j) * 40 + n * 16 + lr] = f2bf(pf);            \
      }                                                                          \
    }                                                                            \
    if (DOS) asm volatile("s_waitcnt vmcnt(2) lgkmcnt(0)" ::: "memory");         \
    else     asm volatile("s_waitcnt vmcnt(0) lgkmcnt(0)" ::: "memory");         \
    __builtin_amdgcn_s_barrier();                                                \
    bf16x8 pa[4];                                                                \
    _Pragma("unroll") for (int m = 0; m < 4; ++m)                                \
        pa[m] = *(const bf16x8*)&ldsP[(m * 16 + lr) * 40 + kg * 8];              \
    _Pragma("unroll") for (int m = 0; m < 4; ++m)                                \
        _Pragma("unroll") for (int n = 0; n < 4; ++n)                            \
            acc[m][n] = __builtin_amdgcn_mfma_f32_16x16x32_bf16(pa[m], b_[n],    \
                                                                acc[m][n], 0, 0, 0); \
    asm volatile("s_waitcnt vmcnt(0) lgkmcnt(0)" ::: "memory");                  \
    __builtin_amdgcn_s_barrier();                                                \
  }

  for (int tp = 0; tp < 13; ++tp) {
    FA_STEP(2 * tp, 0, 1);
    FA_STEP(2 * tp + 1, 1, 1);
  }
  FA_STEP(26, 0, 1);
  FA_STEP(27, 1, 0);
#undef FA_STEP

  // Z-partials (S identical in both col-halves; only ch==0 writes)
  if (ch == 0) {
#pragma unroll
    for (int j = 0; j < 4; ++j) {
#pragma unroll
      for (int msk = 1; msk < 16; msk <<= 1)
        zacc[j] += __shfl_xor(zacc[j], msk, 64);
    }
    if (lr == 0) {
#pragma unroll
      for (int j = 0; j < 4; ++j)
        Zp[((long)b * PVSPLIT + z) * NP + m0 + wave * 16 + kg * 4 + j] = zacc[j];
    }
  }

  // write bf16 partial tile [64 rows][256 cols at ch*256]
  u16* out = Ppart + (long)(b * PVSPLIT + z) * NP * DO_;
#pragma unroll
  for (int m = 0; m < 4; ++m) {
#pragma unroll
    for (int n = 0; n < 4; ++n) {
      int col = ch * 256 + wave * 64 + n * 16 + lr;
#pragma unroll
      for (int j = 0; j < 4; ++j) {
        int row = m0 + m * 16 + kg * 4 + j;
        out[(long)row * DO_ + col] = f2bf(acc[m][n][j]);
      }
    }
  }
}

// ---------- small kernels ----------
__global__ void k_transpose_cast(const float* __restrict__ in, u16* __restrict__ out,
                                 int R, int C, int Cp, int out_ld,
                                 long in_bs, long out_bs) {
  __shared__ float t[32][33];
  long b = blockIdx.z;
  int c0 = blockIdx.x * 32, r0 = blockIdx.y * 32;
  int tx = threadIdx.x, ty = threadIdx.y;
#pragma unroll
  for (int i = 0; i < 32; i += 8) {
    int r = r0 + ty + i, c = c0 + tx;
    t[ty + i][tx] = (r < R && c < C) ? in[b * in_bs + (long)r * C + c] : 0.f;
  }
  __syncthreads();
#pragma unroll
  for (int i = 0; i < 32; i += 8) {
    int c = c0 + ty + i, r = r0 + tx;
    if (c < Cp && r < R)
      out[b * out_bs + (long)c * out_ld + r] = f2bf(t[tx][ty + i]);
  }
}

// cast f32 [R][Cin] -> bf16 [R][Cout] with zero pad, 4 cols/thread vectorized
__global__ void k_cast_pad4(const float* __restrict__ in, u16* __restrict__ out,
                            int Cin, int Cout, long in_bs, long out_bs) {
  int c4 = (blockIdx.x * 256 + threadIdx.x) * 4;
  int r = blockIdx.y;
  long b = blockIdx.z;
  if (c4 >= Cout) return;
  uint2 o = {0u, 0u};
  if (c4 < Cin) {
    float4 v = *(const float4*)&in[b * in_bs + (long)r * Cin + c4];
    o.x = (unsigned)f2bf(v.x) | ((unsigned)f2bf(v.y) << 16);
    o.y = (unsigned)f2bf(v.z) | ((unsigned)f2bf(v.w) << 16);
  }
  *(uint2*)&out[b * out_bs + (long)r * Cout + c4] = o;
}

// weights: wruh[1024][512] (h-halves of wr,wu); wruxc[1536][512] (x-halves of
// wr,wu,wc); wch[512][512] (h-half of wc); m<2 rows also emit bias_ru.
__global__ void k_build_w(const float* __restrict__ wr_, const float* __restrict__ wu_,
                          const float* __restrict__ wc_,
                          const float* __restrict__ br_, const float* __restrict__ bu_,
                          u16* __restrict__ wruh, u16* __restrict__ wruxc,
                          u16* __restrict__ wch, float* __restrict__ bias) {
  int k = blockIdx.x * 256 + threadIdx.x;  // 0..511
  int m = blockIdx.y;                      // 0..3071
  if (k >= 512) return;
  if (m < 2) bias[m * 512 + k] = (m == 0) ? br_[k] : bu_[k];
  if (m < 1024) {
    const float* src = (m < 512) ? wr_ : wu_;
    wruh[m * 512 + k] = f2bf(src[(m & 511) * 1024 + 512 + k]);
  } else if (m < 2560) {
    int n = m - 1024;
    const float* src = (n < 512) ? wr_ : ((n < 1024) ? wu_ : wc_);
    wruxc[n * 512 + k] = f2bf(src[(n & 511) * 1024 + k]);
  } else {
    int n = m - 2560;
    wch[n * 512 + k] = f2bf(wc_[n * 1024 + 512 + k]);
  }
}

// memTb[b][q][o] = bf16( sum_z Ppart[b*PVSPLIT+z][q][o] / sum_z Zp[b][z][q] )
__global__ void k_reduce_mem(const u16* __restrict__ Ppart, const float* __restrict__ Zp,
                             u16* __restrict__ memTb) {
  long t = (long)blockIdx.x * 256 + threadIdx.x;   // uint4 index (8 bf16)
  const long bs = (long)NP * DO_;
  if (t >= (long)NB * bs / 8) return;
  long flat = t * 8;
  int b = (int)(flat / bs);
  long r = flat - (long)b * bs;
  int q = (int)(r / DO_);
  float s[8];
#pragma unroll
  for (int e = 0; e < 8; ++e) s[e] = 0.f;
  float zs = 0.f;
#pragma unroll
  for (int z = 0; z < PVSPLIT; ++z) {
    uint4 v = *(const uint4*)&Ppart[(long)(b * PVSPLIT + z) * bs + r];
    s[0] += bf2f((u16)(v.x & 0xffff)); s[1] += bf2f((u16)(v.x >> 16));
    s[2] += bf2f((u16)(v.y & 0xffff)); s[3] += bf2f((u16)(v.y >> 16));
    s[4] += bf2f((u16)(v.z & 0xffff)); s[5] += bf2f((u16)(v.z >> 16));
    s[6] += bf2f((u16)(v.w & 0xffff)); s[7] += bf2f((u16)(v.w >> 16));
    zs += Zp[((long)b * PVSPLIT + z) * NP + q];
  }
  float iz = 1.f / zs;
  uint4 o;
  o.x = (unsigned)f2bf(s[0] * iz) | ((unsigned)f2bf(s[1] * iz) << 16);
  o.y = (unsigned)f2bf(s[2] * iz) | ((unsigned)f2bf(s[3] * iz) << 16);
  o.z = (unsigned)f2bf(s[4] * iz) | ((unsigned)f2bf(s[5] * iz) << 16);
  o.w = (unsigned)f2bf(s[6] * iz) | ((unsigned)f2bf(s[7] * iz) << 16);
  *(uint4*)&memTb[(long)b * bs + r] = o;
}

__global__ void k_copy_q0(const float4* __restrict__ src, float4* __restrict__ dst) {
  int idx = blockIdx.x * 256 + threadIdx.x;
  long b = blockIdx.z;
  const long n4 = (long)DO_ * HW / 4;  // 199680
  if (idx < n4)
    dst[b * ((long)1024 * HW / 4) + n4 + idx] = src[b * n4 + idx];
}

// ---------- host ----------
extern "C" void kernel_launch(void* const* d_in, const int* in_sizes, int n_in,
                              void* d_out, int out_size, void* d_ws, size_t ws_size,
                              hipStream_t stream) {
  const float* m_in  = (const float*)d_in[0];
  const float* m_out = (const float*)d_in[1];
  const float* q_in  = (const float*)d_in[2];
  const float* q_out = (const float*)d_in[3];
  const float* wr    = (const float*)d_in[4];
  const float* br    = (const float*)d_in[5];
  const float* wu    = (const float*)d_in[6];
  const float* bu    = (const float*)d_in[7];
  const float* wc    = (const float*)d_in[8];
  const float* bc    = (const float*)d_in[9];
  float* dout = (float*)d_out;

  // workspace layout
  char* p = (char*)d_ws;
  size_t off = 0;
  auto alloc = [&](size_t bytes) { void* r = p + off; off += (bytes + 255) & ~(size_t)255; return r; };
  u16*   miT    = (u16*)alloc((size_t)NB * KP * DE * 2);       // [b][k][128]
  u16*   qiT    = (u16*)alloc((size_t)NB * NP * DE * 2);       // [b][q][128]
  float* Zp     = (float*)alloc((size_t)NB * PVSPLIT * NP * 4);
  u16*   moutb  = (u16*)alloc((size_t)NB * DO_ * KP * 2);      // [b][o][k]
  u16*   memTb  = (u16*)alloc((size_t)NB * NP * DO_ * 2);      // [b][q][o]
  // chru,U,XRb,Qfin contiguous: fa partials (28 * NP*DO_*2 = 47.7MB) alias
  // this span (all four dead until after k_reduce_mem). Qfin itself is unused
  // (cand writes d_out directly) but stays allocated for the alias.
  u16*   chru   = (u16*)alloc((size_t)NB * NP * 1024 * 2);     // [b][q][r|u]
  u16*   U      = (u16*)alloc((size_t)NB * NP * DO_ * 2);
  u16*   XRb    = (u16*)alloc((size_t)NB * NP * 1024 * 2);
  float* Qfin   = (float*)alloc((size_t)NB * NP * DO_ * 4);
  (void)Qfin;
  u16*   XRa    = (u16*)alloc((size_t)NB * NP * 1024 * 2);     // [b][q][x|rh]
  u16*   Cx     = (u16*)alloc((size_t)NB * NP * 512 * 2);      // cand X-partial
  u16*   wruh   = (u16*)alloc((size_t)1024 * 512 * 2);
  u16*   wruxc  = (u16*)alloc((size_t)1536 * 512 * 2);
  u16*   wch    = (u16*)alloc((size_t)512 * 512 * 2);
  float* biasru = (float*)alloc((size_t)1024 * 4);
  u16*   Ppart  = (u16*)chru;      // [NB*PVSPLIT][NP][DO_] bf16, alias
  if (off > ws_size) return;

  // --- prep: weights (+bias folded in) ---
  k_build_w<<<dim3(2, 3072), 256, 0, stream>>>(wr, wu, wc, br, bu,
                                               wruh, wruxc, wch, biasru);
  // --- prep: inputs ---
  k_cast_pad4<<<dim3(7, 512, NB), 256, 0, stream>>>(
      m_out, moutb, THW, KP, (long)DO_ * THW, (long)DO_ * KP);
  k_transpose_cast<<<dim3(196, 4, NB), dim3(32, 8), 0, stream>>>(
      m_in, miT, DE, THW, KP, DE, (long)DE * THW, (long)KP * DE);
  k_transpose_cast<<<dim3(52, 4, NB), dim3(32, 8), 0, stream>>>(
      q_in, qiT, DE, HW, NP, DE, (long)DE * HW, (long)NP * DE);
  k_transpose_cast<<<dim3(52, 16, NB), dim3(32, 8), 0, stream>>>(
      q_out, XRa, DO_, HW, NP, 1024, (long)DO_ * HW, (long)NP * 1024);

  // --- fused attention: Ppart/Zp = flash(Q,K,V) partials (split-K x7,
  //     col-split x2 for occupancy) ---
  gemm_fa<<<dim3(1456), 256, 0, stream>>>(qiT, miT, moutb, Ppart, Zp);
  k_reduce_mem<<<dim3(1664), 256, 0, stream>>>(Ppart, Zp, memTb);

  // --- Chru(bf16) = memT @ Wruh^T + [br;bu] ---
  gk_chru<<<dim3(26, 8, NB), 256, 0, stream>>>(
      memTb, wruh, DO_, DO_, DO_, (long)NP * DO_, 0,
      nullptr, 0, 0, chru, (long)NP * 1024, 1024, nullptr, 0,
      biasru, 0, nullptr, 0, nullptr, 0, nullptr, 0, 0, 0.f);

  // --- GRU layers ---
  u16* xr[2] = {XRa, XRb};
  for (int l = 0; l < PROP; ++l) {
    u16* cur = xr[l & 1];
    u16* nxt = xr[(l + 1) & 1];
    // gates r,u + cand-X partial: N=1536 over [Wr_x|Wu_x|Wc_x], 128-tile
    gk_gates<<<dim3(13, 12, NB), 256, 0, stream>>>(
        cur, wruxc, DO_, 1024, DO_, (long)NP * 1024, 0,
        U, (long)NP * DO_, DO_, cur, (long)NP * 1024, 1024,
        Cx, (long)NP * 512,
        chru, (long)NP * 1024, memTb, (long)NP * DO_, nullptr, 0,
        nullptr, 0, 0, 0.f);
    // candidate (K=512 RH half) + GRU update; last layer writes d_out direct
    gk_cand<<<dim3(26, 4, NB), 256, 0, stream>>>(
        cur + 512, wch, DO_, 1024, DO_, (long)NP * 1024, 0,
        (l == PROP - 1) ? (void*)dout : nullptr, (long)1024 * HW, HW,
        nxt, (long)NP * 1024, 1024, nullptr, 0,
        bc, 0, U, (long)NP * DO_, memTb, (long)NP * DO_,
        Cx, (long)NP * 512, HW, 0.f);
  }

  // --- outputs: channels 512..1023 = q0 ---
  k_copy_q0<<<dim3(780, 1, NB), 256, 0, stream>>>((const float4*)q_out, (float4*)dout);
}

// Round 21
// 624.868 us; speedup vs baseline: 1.0116x; 1.0116x over previous
//
#include <hip/hip_runtime.h>
#include <hip/hip_bf16.h>
#include <math.h>

typedef unsigned short u16;
typedef __attribute__((ext_vector_type(8))) short bf16x8;
typedef __attribute__((ext_vector_type(4))) float f32x4;

// ---------- helpers ----------
__device__ __forceinline__ u16 f2bf(float f) {
  union { float f; unsigned u; } x; x.f = f;
  unsigned r = x.u + 0x7fffu + ((x.u >> 16) & 1u);
  return (u16)(r >> 16);
}
__device__ __forceinline__ float bf2f(u16 h) {
  union { unsigned u; float f; } x; x.u = ((unsigned)h) << 16;
  return x.f;
}
__device__ __forceinline__ float sigmf(float x) {
  x = fminf(fmaxf(x, -30.f), 30.f);
  return 1.f / (1.f + __expf(-x));
}
__device__ __forceinline__ float tanh_fast(float x) {
  x = fminf(fmaxf(x, -15.f), 15.f);
  float t = __expf(2.f * x);
  return (t - 1.f) / (t + 1.f);
}

// counted vmcnt wait (T4)
template<int N> __device__ __forceinline__ void wait_vmcnt() {
  if constexpr (N == 0)       asm volatile("s_waitcnt vmcnt(0)" ::: "memory");
  else if constexpr (N == 4)  asm volatile("s_waitcnt vmcnt(4)" ::: "memory");
  else if constexpr (N == 6)  asm volatile("s_waitcnt vmcnt(6)" ::: "memory");
  else if constexpr (N == 8)  asm volatile("s_waitcnt vmcnt(8)" ::: "memory");
  else static_assert(N == 0, "add vmcnt case");
}

// ---------- problem constants ----------
#define NB 4
#define DE 128
#define DO_ 512
#define HW 1560
#define THW 6240
#define NP 1664   // HW padded to 13*128
#define KP 6272   // THW padded to 49*128
#define PROP 5
#define PVSPLIT 7
#define PVKC 896  // 6272/7 = 28*32
#define SCALE 0.08838834764831845f

// ---------- generic bf16 GEMM core: C[M,N] = A[M,K] * Bt[N,K]^T ----------
// Tile BMT x 128, K-step BKT, 4 waves, 16x16x32 MFMA, global_load_lds
// double-buffer, counted vmcnt + raw barriers (chain kernels, 3D grid).
template<int MODE, int BMT, int BKT>
__device__ __forceinline__
void gemm_core(const u16* __restrict__ A, const u16* __restrict__ Bt,
               int K, int lda, int ldb, long a_bs, long b_bs,
               void* __restrict__ out0v, long o0_bs, int ld0,
               u16* __restrict__ out1, long o1_bs, int ld1,
               u16* __restrict__ out2, long o2_bs,
               const void* __restrict__ e0v, long e0_bs,
               const void* __restrict__ e1v, long e1_bs,
               const void* __restrict__ e2v, long e2_bs,
               const void* __restrict__ e3v, long e3_bs,
               int nvalid, float scale)
{
  constexpr int WR = BMT / 64;        // wave rows (2 or 1)
  constexpr int WC = 4 / WR;          // wave cols (2 or 4)
  constexpr int NF = 8 / WC;          // 16-wide n-frags per wave
  constexpr int KK = BKT / 32;        // k-subtiles per step
  constexpr int ASLOT = BMT * BKT / 8;
  constexpr int BSLOT = 128 * BKT / 8;
  constexpr int NISS = (ASLOT + BSLOT) / 256;
  constexpr int RSH = (BMT == 128) ? 7 : 6;
  __shared__ u16 lds[2][ASLOT + BSLOT][8];

  const int tid = threadIdx.x;
  const int wave = tid >> 6, lane = tid & 63;
  const int kg = lane >> 4, lr = lane & 15;
  const int wrw = wave / WC, wcw = wave % WC;
  const long b = blockIdx.z;
  const int m0 = blockIdx.x * BMT, n0 = blockIdx.y * 128;
  A += b * a_bs; Bt += b * b_bs;

  float* out0f = (float*)out0v;
  u16* out0h = (u16*)out0v;
  const float* e0f = (const float*)e0v;
  const u16* e0h = (const u16*)e0v;
  const u16* e1h = (const u16*)e1v;
  const u16* e2h = (const u16*)e2v;
  const u16* e3h = (const u16*)e3v;

  auto stage = [&](int buf, int kt) {
#pragma unroll
    for (int i = 0; i < NISS; ++i) {
      int s = tid + 256 * i;
      const u16* src;
      if (s < ASLOT) {
        int row = s & (BMT - 1), g = s >> RSH;
        src = A + (long)(m0 + row) * lda + kt + g * 8;
      } else {
        int s2 = s - ASLOT;
        int row = s2 & 127, g = s2 >> 7;
        src = Bt + (long)(n0 + row) * ldb + kt + g * 8;
      }
      __builtin_amdgcn_global_load_lds(
          (const __attribute__((address_space(1))) void*)src,
          (__attribute__((address_space(3))) void*)&lds[buf][wave * 64 + 256 * i][0],
          16, 0, 0);
    }
  };

  f32x4 acc[4][NF];
#pragma unroll
  for (int m = 0; m < 4; ++m)
#pragma unroll
    for (int n = 0; n < NF; ++n) acc[m][n] = (f32x4){0.f, 0.f, 0.f, 0.f};

  const int nt = K / BKT;
  stage(0, 0);
  for (int t = 0; t < nt; ++t) {
    int cur = t & 1;
    if (t + 1 < nt) {
      stage(cur ^ 1, (t + 1) * BKT);   // next tile stays in flight across barrier
      wait_vmcnt<NISS>();
    } else {
      wait_vmcnt<0>();
    }
    __builtin_amdgcn_s_barrier();
    bf16x8 af[KK][4], bfr[KK][NF];
#pragma unroll
    for (int kk = 0; kk < KK; ++kk) {
#pragma unroll
      for (int m = 0; m < 4; ++m)
        af[kk][m] = *(const bf16x8*)&lds[cur][(kk * 4 + kg) * BMT + wrw * 64 + m * 16 + lr][0];
#pragma unroll
      for (int n = 0; n < NF; ++n)
        bfr[kk][n] = *(const bf16x8*)&lds[cur][ASLOT + (kk * 4 + kg) * 128 + (wcw * NF + n) * 16 + lr][0];
    }
#pragma unroll
    for (int kk = 0; kk < KK; ++kk)
#pragma unroll
      for (int m = 0; m < 4; ++m)
#pragma unroll
        for (int n = 0; n < NF; ++n)
          acc[m][n] = __builtin_amdgcn_mfma_f32_16x16x32_bf16(af[kk][m], bfr[kk][n], acc[m][n], 0, 0, 0);
    __builtin_amdgcn_s_barrier();
  }

  // frag elem j -> row = m0+wrw*64+m*16+kg*4+j, col = n0+(wcw*NF+n)*16+lr
#pragma unroll
  for (int m = 0; m < 4; ++m) {
    int rloc = wrw * 64 + m * 16 + kg * 4;
#pragma unroll
    for (int n = 0; n < NF; ++n) {
      int col = n0 + (wcw * NF + n) * 16 + lr;
#pragma unroll
      for (int j = 0; j < 4; ++j) {
        long row = m0 + rloc + j;
        float v = acc[m][n][j];
        if constexpr (MODE == 2) {        // Chru(bf16) = memT @ Wruh^T + bias_ru
          out1[b * o1_bs + row * ld1 + col] = f2bf(v + e0f[col]);
        } else if constexpr (MODE == 3) { // gates r,u + cand-X partial
          if (col < 1024) {
            float gt = sigmf(v + bf2f(e0h[b * e0_bs + row * 1024 + col]));
            if (col < 512)                // r -> RH = r*mem into XR cols 512..1023
              out1[b * o1_bs + row * ld1 + 512 + col] =
                  f2bf(gt * bf2f(e1h[b * e1_bs + row * 512 + col]));
            else                          // u -> U (bf16)
              out0h[b * o0_bs + row * ld0 + (col - 512)] = f2bf(gt);
          } else {                        // Cx = X @ Wc_x (raw logit partial)
            out2[b * o2_bs + row * 512 + (col - 1024)] = f2bf(v);
          }
        } else if constexpr (MODE == 4) { // candidate (RH half) + GRU update
          float cg = tanh_fast(v + bf2f(e3h[b * e3_bs + row * 512 + col]) + e0f[col]);
          float u = bf2f(e1h[b * e1_bs + row * 512 + col]);
          float mm = bf2f(e2h[b * e2_bs + row * 512 + col]);
          float x = mm * (1.f - u) + u * cg;
          out1[b * o1_bs + row * ld1 + col] = f2bf(x);
          // last layer: write d_out directly, transposed [b][col][row], row<HW
          if (out0f && row < nvalid)
            out0f[b * o0_bs + (long)col * ld0 + row] = x;
        }
      }
    }
  }
}

#define GEMM_ARGS                                                              \
  const u16* __restrict__ A, const u16* __restrict__ Bt, int K, int lda,       \
  int ldb, long a_bs, long b_bs, void* __restrict__ out0v, long o0_bs,         \
  int ld0, u16* __restrict__ out1, long o1_bs, int ld1,                        \
  u16* __restrict__ out2, long o2_bs,                                          \
  const void* __restrict__ e0v, long e0_bs, const void* __restrict__ e1v,      \
  long e1_bs, const void* __restrict__ e2v, long e2_bs,                        \
  const void* __restrict__ e3v, long e3_bs, int nvalid, float scale
#define GEMM_PASS A, Bt, K, lda, ldb, a_bs, b_bs, out0v, o0_bs, ld0, out1,     \
  o1_bs, ld1, out2, o2_bs, e0v, e0_bs, e1v, e1_bs, e2v, e2_bs, e3v, e3_bs,     \
  nvalid, scale

__global__ __launch_bounds__(256) void gk_chru(GEMM_ARGS)   { gemm_core<2, 64, 64>(GEMM_PASS); }
__global__ __launch_bounds__(256) void gk_gates(GEMM_ARGS)  { gemm_core<3, 128, 64>(GEMM_PASS); }
__global__ __launch_bounds__(256) void gk_cand(GEMM_ARGS)   { gemm_core<4, 64, 64>(GEMM_PASS); }

// ========== fused attention: Ppart[b,z] = exp(Q@K^T*s) @ moutb^T ==========
// Flash-style (round-15/19 proven version, 137us): never materializes Pt.
// Per block (64 q-rows, 896-kv chunk, all 512 o-cols): Q-tile in LDS (staged
// once); per 32-kv step: Kc staged to double-buffered LDS (loads ride across
// barriers), S = Q@Kc^T (8 MFMA/wave), exp+mask -> P in single-buffer padded
// LDS, Z accumulated in regs, PV (32 MFMA/wave) with reg-loaded moutb
// B-frags. Z reduced via shfl at end. XCD-pinned decode.
__global__ __launch_bounds__(256, 2)
void gemm_fa(const u16* __restrict__ qiT, const u16* __restrict__ miT,
             const u16* __restrict__ moutb,
             u16* __restrict__ Ppart, float* __restrict__ Zp)
{
  const int bid = blockIdx.x;            // 0..727
  const int xcd = bid & 7, i = bid >> 3; // i 0..90
  const int s = xcd * 91 + i;            // 0..727
  const int pair = s / 26, mb = s - pair * 26;
  const int b = pair / PVSPLIT, z = pair - b * PVSPLIT;
  const int m0 = mb * 64;
  const int k0 = z * PVKC;               // 28 steps of 32 kv

  const int tid = threadIdx.x;
  const int wave = tid >> 6, lane = tid & 63;
  const int kg = lane >> 4, lr = lane & 15;

  __shared__ u16 ldsQ[1024 * 8];         // 16 KB, persistent
  __shared__ u16 ldsK[2][512 * 8];       // 8 KB each
  __shared__ u16 ldsP[64 * 40];          // [q][kv] pad-40 : 5 KB

  const u16* Qb = qiT + (long)b * NP * DE;
  const u16* Mb = miT + (long)b * KP * DE;
  const u16* B0 = moutb + (long)b * DO_ * KP +
                  (long)(wave * 128 + lr) * KP + kg * 8;

  auto stageK = [&](int buf, int ts) {
#pragma unroll
    for (int i2 = 0; i2 < 2; ++i2) {
      int s2 = tid + 256 * i2;             // 0..511
      int row = s2 & 31, g = s2 >> 5;
      const u16* src = Mb + (long)(k0 + ts * 32 + row) * DE + g * 8;
      __builtin_amdgcn_global_load_lds(
          (const __attribute__((address_space(1))) void*)src,
          (__attribute__((address_space(3))) void*)&ldsK[buf][(wave * 64 + 256 * i2) * 8],
          16, 0, 0);
    }
  };

  // prologue: stage Q (once) + Kc(0); full drain + barrier
#pragma unroll
  for (int i2 = 0; i2 < 4; ++i2) {
    int s2 = tid + 256 * i2;               // 0..1023
    int row = s2 & 63, g = s2 >> 6;
    const u16* src = Qb + (long)(m0 + row) * DE + g * 8;
    __builtin_amdgcn_global_load_lds(
        (const __attribute__((address_space(1))) void*)src,
        (__attribute__((address_space(3))) void*)&ldsQ[(wave * 64 + 256 * i2) * 8],
        16, 0, 0);
  }
  stageK(0, 0);
  __syncthreads();

  f32x4 acc[4][8];
#pragma unroll
  for (int m = 0; m < 4; ++m)
#pragma unroll
    for (int n = 0; n < 8; ++n) acc[m][n] = (f32x4){0.f, 0.f, 0.f, 0.f};
  float zacc[4] = {0.f, 0.f, 0.f, 0.f};
  bf16x8 b_[8];

#define FA_STEP(T, CUR, DOS)                                                     \
  {                                                                              \
    _Pragma("unroll") for (int n = 0; n < 8; ++n)                                \
        b_[n] = *(const bf16x8*)&B0[(long)n * 16 * KP + k0 + (T) * 32];          \
    if (DOS) stageK((CUR) ^ 1, (T) + 1);                                         \
    bf16x8 qf[4], kc[2][4];                                                      \
    _Pragma("unroll") for (int kk = 0; kk < 4; ++kk)                             \
        qf[kk] = *(const bf16x8*)&ldsQ[((kk * 4 + kg) * 64 + wave * 16 + lr) * 8]; \
    _Pragma("unroll") for (int n = 0; n < 2; ++n)                                \
        _Pragma("unroll") for (int kk = 0; kk < 4; ++kk)                         \
            kc[n][kk] = *(const bf16x8*)&ldsK[CUR][((kk * 4 + kg) * 32 + n * 16 + lr) * 8]; \
    f32x4 sacc[2];                                                               \
    sacc[0] = (f32x4){0.f, 0.f, 0.f, 0.f};                                       \
    sacc[1] = (f32x4){0.f, 0.f, 0.f, 0.f};                                       \
    _Pragma("unroll") for (int kk = 0; kk < 4; ++kk)                             \
        _Pragma("unroll") for (int n = 0; n < 2; ++n)                            \
            sacc[n] = __builtin_amdgcn_mfma_f32_16x16x32_bf16(qf[kk], kc[n][kk], \
                                                              sacc[n], 0, 0, 0); \
    _Pragma("unroll") for (int n = 0; n < 2; ++n) {                              \
      bool valid = (k0 + (T) * 32 + n * 16 + lr) < THW;                          \
      _Pragma("unroll") for (int j = 0; j < 4; ++j) {                            \
        float pf = valid ? __expf(sacc[n][j] * SCALE) : 0.f;                     \
        zacc[j] += pf;                                                           \
        ldsP[(wave * 16 + kg * 4 + j) * 40 + n * 16 + lr] = f2bf(pf);            \
      }                                                                          \
    }                                                                            \
    if (DOS) asm volatile("s_waitcnt vmcnt(2) lgkmcnt(0)" ::: "memory");         \
    else     asm volatile("s_waitcnt vmcnt(0) lgkmcnt(0)" ::: "memory");         \
    __builtin_amdgcn_s_barrier();                                                \
    bf16x8 pa[4];                                                                \
    _Pragma("unroll") for (int m = 0; m < 4; ++m)                                \
        pa[m] = *(const bf16x8*)&ldsP[(m * 16 + lr) * 40 + kg * 8];              \
    _Pragma("unroll") for (int m = 0; m < 4; ++m)                                \
        _Pragma("unroll") for (int n = 0; n < 8; ++n)                            \
            acc[m][n] = __builtin_amdgcn_mfma_f32_16x16x32_bf16(pa[m], b_[n],    \
                                                                acc[m][n], 0, 0, 0); \
    asm volatile("s_waitcnt vmcnt(0) lgkmcnt(0)" ::: "memory");                  \
    __builtin_amdgcn_s_barrier();                                                \
  }

  for (int tp = 0; tp < 13; ++tp) {
    FA_STEP(2 * tp, 0, 1);
    FA_STEP(2 * tp + 1, 1, 1);
  }
  FA_STEP(26, 0, 1);
  FA_STEP(27, 1, 0);
#undef FA_STEP

  // Z-partials: reduce over lr (xor 1,2,4,8 stay within kg group)
#pragma unroll
  for (int j = 0; j < 4; ++j) {
#pragma unroll
    for (int msk = 1; msk < 16; msk <<= 1)
      zacc[j] += __shfl_xor(zacc[j], msk, 64);
  }
  if (lr == 0) {
#pragma unroll
    for (int j = 0; j < 4; ++j)
      Zp[((long)b * PVSPLIT + z) * NP + m0 + wave * 16 + kg * 4 + j] = zacc[j];
  }

  // write bf16 partial tile [64][512]
  u16* out = Ppart + (long)(b * PVSPLIT + z) * NP * DO_;
#pragma unroll
  for (int m = 0; m < 4; ++m) {
#pragma unroll
    for (int n = 0; n < 8; ++n) {
      int col = wave * 128 + n * 16 + lr;
#pragma unroll
      for (int j = 0; j < 4; ++j) {
        int row = m0 + m * 16 + kg * 4 + j;
        out[(long)row * DO_ + col] = f2bf(acc[m][n][j]);
      }
    }
  }
}

// ---------- small kernels ----------
__global__ void k_transpose_cast(const float* __restrict__ in, u16* __restrict__ out,
                                 int R, int C, int Cp, int out_ld,
                                 long in_bs, long out_bs) {
  __shared__ float t[32][33];
  long b = blockIdx.z;
  int c0 = blockIdx.x * 32, r0 = blockIdx.y * 32;
  int tx = threadIdx.x, ty = threadIdx.y;
#pragma unroll
  for (int i = 0; i < 32; i += 8) {
    int r = r0 + ty + i, c = c0 + tx;
    t[ty + i][tx] = (r < R && c < C) ? in[b * in_bs + (long)r * C + c] : 0.f;
  }
  __syncthreads();
#pragma unroll
  for (int i = 0; i < 32; i += 8) {
    int c = c0 + ty + i, r = r0 + tx;
    if (c < Cp && r < R)
      out[b * out_bs + (long)c * out_ld + r] = f2bf(t[tx][ty + i]);
  }
}

// cast f32 [R][Cin] -> bf16 [R][Cout] with zero pad, 4 cols/thread vectorized
__global__ void k_cast_pad4(const float* __restrict__ in, u16* __restrict__ out,
                            int Cin, int Cout, long in_bs, long out_bs) {
  int c4 = (blockIdx.x * 256 + threadIdx.x) * 4;
  int r = blockIdx.y;
  long b = blockIdx.z;
  if (c4 >= Cout) return;
  uint2 o = {0u, 0u};
  if (c4 < Cin) {
    float4 v = *(const float4*)&in[b * in_bs + (long)r * Cin + c4];
    o.x = (unsigned)f2bf(v.x) | ((unsigned)f2bf(v.y) << 16);
    o.y = (unsigned)f2bf(v.z) | ((unsigned)f2bf(v.w) << 16);
  }
  *(uint2*)&out[b * out_bs + (long)r * Cout + c4] = o;
}

// weights: wruh[1024][512] (h-halves of wr,wu); wruxc[1536][512] (x-halves of
// wr,wu,wc); wch[512][512] (h-half of wc); m<2 rows also emit bias_ru.
__global__ void k_build_w(const float* __restrict__ wr_, const float* __restrict__ wu_,
                          const float* __restrict__ wc_,
                          const float* __restrict__ br_, const float* __restrict__ bu_,
                          u16* __restrict__ wruh, u16* __restrict__ wruxc,
                          u16* __restrict__ wch, float* __restrict__ bias) {
  int k = blockIdx.x * 256 + threadIdx.x;  // 0..511
  int m = blockIdx.y;                      // 0..3071
  if (k >= 512) return;
  if (m < 2) bias[m * 512 + k] = (m == 0) ? br_[k] : bu_[k];
  if (m < 1024) {
    const float* src = (m < 512) ? wr_ : wu_;
    wruh[m * 512 + k] = f2bf(src[(m & 511) * 1024 + 512 + k]);
  } else if (m < 2560) {
    int n = m - 1024;
    const float* src = (n < 512) ? wr_ : ((n < 1024) ? wu_ : wc_);
    wruxc[n * 512 + k] = f2bf(src[(n & 511) * 1024 + k]);
  } else {
    int n = m - 2560;
    wch[n * 512 + k] = f2bf(wc_[n * 1024 + 512 + k]);
  }
}

// memTb[b][q][o] = bf16( sum_z Ppart[b*PVSPLIT+z][q][o] / sum_z Zp[b][z][q] )
__global__ void k_reduce_mem(const u16* __restrict__ Ppart, const float* __restrict__ Zp,
                             u16* __restrict__ memTb) {
  long t = (long)blockIdx.x * 256 + threadIdx.x;   // uint4 index (8 bf16)
  const long bs = (long)NP * DO_;
  if (t >= (long)NB * bs / 8) return;
  long flat = t * 8;
  int b = (int)(flat / bs);
  long r = flat - (long)b * bs;
  int q = (int)(r / DO_);
  float s[8];
#pragma unroll
  for (int e = 0; e < 8; ++e) s[e] = 0.f;
  float zs = 0.f;
#pragma unroll
  for (int z = 0; z < PVSPLIT; ++z) {
    uint4 v = *(const uint4*)&Ppart[(long)(b * PVSPLIT + z) * bs + r];
    s[0] += bf2f((u16)(v.x & 0xffff)); s[1] += bf2f((u16)(v.x >> 16));
    s[2] += bf2f((u16)(v.y & 0xffff)); s[3] += bf2f((u16)(v.y >> 16));
    s[4] += bf2f((u16)(v.z & 0xffff)); s[5] += bf2f((u16)(v.z >> 16));
    s[6] += bf2f((u16)(v.w & 0xffff)); s[7] += bf2f((u16)(v.w >> 16));
    zs += Zp[((long)b * PVSPLIT + z) * NP + q];
  }
  float iz = 1.f / zs;
  uint4 o;
  o.x = (unsigned)f2bf(s[0] * iz) | ((unsigned)f2bf(s[1] * iz) << 16);
  o.y = (unsigned)f2bf(s[2] * iz) | ((unsigned)f2bf(s[3] * iz) << 16);
  o.z = (unsigned)f2bf(s[4] * iz) | ((unsigned)f2bf(s[5] * iz) << 16);
  o.w = (unsigned)f2bf(s[6] * iz) | ((unsigned)f2bf(s[7] * iz) << 16);
  *(uint4*)&memTb[(long)b * bs + r] = o;
}

__global__ void k_copy_q0(const float4* __restrict__ src, float4* __restrict__ dst) {
  int idx = blockIdx.x * 256 + threadIdx.x;
  long b = blockIdx.z;
  const long n4 = (long)DO_ * HW / 4;  // 199680
  if (idx < n4)
    dst[b * ((long)1024 * HW / 4) + n4 + idx] = src[b * n4 + idx];
}

// ---------- host ----------
extern "C" void kernel_launch(void* const* d_in, const int* in_sizes, int n_in,
                              void* d_out, int out_size, void* d_ws, size_t ws_size,
                              hipStream_t stream) {
  const float* m_in  = (const float*)d_in[0];
  const float* m_out = (const float*)d_in[1];
  const float* q_in  = (const float*)d_in[2];
  const float* q_out = (const float*)d_in[3];
  const float* wr    = (const float*)d_in[4];
  const float* br    = (const float*)d_in[5];
  const float* wu    = (const float*)d_in[6];
  const float* bu    = (const float*)d_in[7];
  const float* wc    = (const float*)d_in[8];
  const float* bc    = (const float*)d_in[9];
  float* dout = (float*)d_out;

  // workspace layout
  char* p = (char*)d_ws;
  size_t off = 0;
  auto alloc = [&](size_t bytes) { void* r = p + off; off += (bytes + 255) & ~(size_t)255; return r; };
  u16*   miT    = (u16*)alloc((size_t)NB * KP * DE * 2);       // [b][k][128]
  u16*   qiT    = (u16*)alloc((size_t)NB * NP * DE * 2);       // [b][q][128]
  float* Zp     = (float*)alloc((size_t)NB * PVSPLIT * NP * 4);
  u16*   moutb  = (u16*)alloc((size_t)NB * DO_ * KP * 2);      // [b][o][k]
  u16*   memTb  = (u16*)alloc((size_t)NB * NP * DO_ * 2);      // [b][q][o]
  // chru,U,XRb,Qfin contiguous: fa partials (28 * NP*DO_*2 = 47.7MB) alias
  // this span (all four dead until after k_reduce_mem). Qfin itself is unused
  // (cand writes d_out directly) but stays allocated for the alias.
  u16*   chru   = (u16*)alloc((size_t)NB * NP * 1024 * 2);     // [b][q][r|u]
  u16*   U      = (u16*)alloc((size_t)NB * NP * DO_ * 2);
  u16*   XRb    = (u16*)alloc((size_t)NB * NP * 1024 * 2);
  float* Qfin   = (float*)alloc((size_t)NB * NP * DO_ * 4);
  (void)Qfin;
  u16*   XRa    = (u16*)alloc((size_t)NB * NP * 1024 * 2);     // [b][q][x|rh]
  u16*   Cx     = (u16*)alloc((size_t)NB * NP * 512 * 2);      // cand X-partial
  u16*   wruh   = (u16*)alloc((size_t)1024 * 512 * 2);
  u16*   wruxc  = (u16*)alloc((size_t)1536 * 512 * 2);
  u16*   wch    = (u16*)alloc((size_t)512 * 512 * 2);
  float* biasru = (float*)alloc((size_t)1024 * 4);
  u16*   Ppart  = (u16*)chru;      // [NB*PVSPLIT][NP][DO_] bf16, alias
  if (off > ws_size) return;

  // --- prep: weights (+bias folded in) ---
  k_build_w<<<dim3(2, 3072), 256, 0, stream>>>(wr, wu, wc, br, bu,
                                               wruh, wruxc, wch, biasru);
  // --- prep: inputs ---
  k_cast_pad4<<<dim3(7, 512, NB), 256, 0, stream>>>(
      m_out, moutb, THW, KP, (long)DO_ * THW, (long)DO_ * KP);
  k_transpose_cast<<<dim3(196, 4, NB), dim3(32, 8), 0, stream>>>(
      m_in, miT, DE, THW, KP, DE, (long)DE * THW, (long)KP * DE);
  k_transpose_cast<<<dim3(52, 4, NB), dim3(32, 8), 0, stream>>>(
      q_in, qiT, DE, HW, NP, DE, (long)DE * HW, (long)NP * DE);
  k_transpose_cast<<<dim3(52, 16, NB), dim3(32, 8), 0, stream>>>(
      q_out, XRa, DO_, HW, NP, 1024, (long)DO_ * HW, (long)NP * 1024);

  // --- fused attention: Ppart/Zp = flash(Q,K,V) partials (split-K x7) ---
  gemm_fa<<<dim3(728), 256, 0, stream>>>(qiT, miT, moutb, Ppart, Zp);
  k_reduce_mem<<<dim3(1664), 256, 0, stream>>>(Ppart, Zp, memTb);

  // --- Chru(bf16) = memT @ Wruh^T + [br;bu] ---
  gk_chru<<<dim3(26, 8, NB), 256, 0, stream>>>(
      memTb, wruh, DO_, DO_, DO_, (long)NP * DO_, 0,
      nullptr, 0, 0, chru, (long)NP * 1024, 1024, nullptr, 0,
      biasru, 0, nullptr, 0, nullptr, 0, nullptr, 0, 0, 0.f);

  // --- GRU layers ---
  u16* xr[2] = {XRa, XRb};
  for (int l = 0; l < PROP; ++l) {
    u16* cur = xr[l & 1];
    u16* nxt = xr[(l + 1) & 1];
    // gates r,u + cand-X partial: N=1536 over [Wr_x|Wu_x|Wc_x], 128-tile
    gk_gates<<<dim3(13, 12, NB), 256, 0, stream>>>(
        cur, wruxc, DO_, 1024, DO_, (long)NP * 1024, 0,
        U, (long)NP * DO_, DO_, cur, (long)NP * 1024, 1024,
        Cx, (long)NP * 512,
        chru, (long)NP * 1024, memTb, (long)NP * DO_, nullptr, 0,
        nullptr, 0, 0, 0.f);
    // candidate (K=512 RH half) + GRU update; last layer writes d_out direct
    gk_cand<<<dim3(26, 4, NB), 256, 0, stream>>>(
        cur + 512, wch, DO_, 1024, DO_, (long)NP * 1024, 0,
        (l == PROP - 1) ? (void*)dout : nullptr, (long)1024 * HW, HW,
        nxt, (long)NP * 1024, 1024, nullptr, 0,
        bc, 0, U, (long)NP * DO_, memTb, (long)NP * DO_,
        Cx, (long)NP * 512, HW, 0.f);
  }

  // --- outputs: channels 512..1023 = q0 ---
  k_copy_q0<<<dim3(780, 1, NB), 256, 0, stream>>>((const float4*)q_out, (float4*)dout);
}